// Round 2
// baseline (182.183 us; speedup 1.0000x reference)
//
#include <hip/hip_runtime.h>
#include <hip/hip_fp16.h>
#include <math.h>

#define CC 64
#define KK 16
#define NNODES 15
#define DD 512      // input feature dim
#define MM 512      // output dim
#define NN 16384    // rows

typedef _Float16 half8 __attribute__((ext_vector_type(8)));
typedef float f32x4 __attribute__((ext_vector_type(4)));
typedef unsigned long long u64;

// ---------------------------------------------------------------------------
// XLA/Eigen fast-tanh for f32 (bit-exact vs JAX's jnp.tanh lowering).
// ---------------------------------------------------------------------------
__device__ __forceinline__ float xla_tanhf(float x) {
    const float kMax = 7.90531110763549805f;
    bool tiny = fabsf(x) < 0.0004f;
    float xc = fminf(fmaxf(x, -kMax), kMax);
    float x2 = __fmul_rn(xc, xc);
    float p = __fmaf_rn(x2, -2.76076847742355e-16f, 2.00018790482477e-13f);
    p = __fmaf_rn(x2, p, -8.60467152213735e-11f);
    p = __fmaf_rn(x2, p, 5.12229709037114e-08f);
    p = __fmaf_rn(x2, p, 1.48572235717979e-05f);
    p = __fmaf_rn(x2, p, 6.37261928875436e-04f);
    p = __fmaf_rn(x2, p, 4.89352455891786e-03f);
    p = __fmul_rn(xc, p);
    float q = __fmaf_rn(x2, 1.19825839466702e-06f, 1.18534705686654e-04f);
    q = __fmaf_rn(x2, q, 2.26843463243900e-03f);
    q = __fmaf_rn(x2, q, 4.89352518554385e-03f);
    return tiny ? x : __fdiv_rn(p, q);
}

// ---------------------------------------------------------------------------
// Kernel 1: pack L (M, C, K) fp32 -> Bpk fp16 in MFMA-B fragment order.
// B operand of mfma_f32_16x16x32_f16: lane l holds B[k=(l>>4)*8+j][col=l&15],
// j = 0..7 packed in 4 VGPRs. Layout: Bpk[ks][mtile][lane] = uint4 (8 halves).
// (round-1 verified: fused_mfma passed with this layout)
// ---------------------------------------------------------------------------
__global__ __launch_bounds__(256) void pack_bfrag(const float* __restrict__ L,
                                                  uint4* __restrict__ Bpk) {
    const int t    = blockIdx.x * 256 + threadIdx.x;  // 0..65535
    const int lane = t & 63;
    const int mtg  = (t >> 6) & 31;                   // global m-tile 0..31
    const int ks   = t >> 11;                         // k-step 0..31
    const int kbase = ks * 32 + ((lane >> 4) << 3);   // 8-aligned k window
    const int c     = kbase >> 4;                     // subspace
    const int slot0 = kbase & 15;                     // 0 or 8
    const int m     = (mtg << 4) + (lane & 15);

    const float* src = L + ((size_t)m * CC + c) * KK + slot0;
    float4 v0 = ((const float4*)src)[0];
    float4 v1 = ((const float4*)src)[1];
    union { half8 h; uint4 u; } pk;
    pk.h[0] = (_Float16)v0.x; pk.h[1] = (_Float16)v0.y;
    pk.h[2] = (_Float16)v0.z; pk.h[3] = (_Float16)v0.w;
    pk.h[4] = (_Float16)v1.x; pk.h[5] = (_Float16)v1.y;
    pk.h[6] = (_Float16)v1.z; pk.h[7] = (_Float16)v1.w;
    Bpk[t] = pk.u;
}

// ---------------------------------------------------------------------------
// Kernel 2: FUSED encode + MFMA decode — occupancy/latency restructure.
// Block: 64 rows x 256 cols, 8 waves (512 thr); wave = 64 rows x 32 cols
// (4 nt x 2 mt). Grid 512 -> 16 waves/CU (4/SIMD), 2x round-1.
// sCodes repacked as u32[(r15*68)+c] (byte nt = code of row nt*16+r15):
// one ds_read_b32 per build-set, <=2-way banks both directions.
// B frags AND code words software-pipelined one full iteration ahead.
// ---------------------------------------------------------------------------
__global__ __launch_bounds__(512, 4) void fused_mfma(const float* __restrict__ I,
                                                     const float* __restrict__ A,
                                                     const float* __restrict__ T,
                                                     const uint4* __restrict__ Bpk,
                                                     float* __restrict__ out) {
    __shared__ float sA[32 * 64];              // TRANSPOSED: [s*4+d][c]
    __shared__ float sT[CC * NNODES];
    __shared__ unsigned sCodes[16 * 68];       // [r15][c] u32: 4 nt codes packed

    const int tid = threadIdx.x;
    for (int i = tid; i < CC * 32; i += 512) sA[(i & 31) * 64 + (i >> 5)] = A[i];
    for (int i = tid; i < CC * NNODES; i += 512) sT[i] = T[i];
    __syncthreads();

    const int w    = tid >> 6;        // wave 0..7
    const int lane = tid & 63;
    const int n0 = (blockIdx.x >> 1) * 64;
    const int m0 = (blockIdx.x & 1) * 256 + w * 32;

    // ---------------- encode (bit-exact round-5 math; 8 rows/thread) ----------------
    {
        const int c = lane;
        const int lvl[NNODES] = {0, 1, 1, 2, 2, 2, 2, 3, 3, 3, 3, 3, 3, 3, 3};
#pragma unroll 2
        for (int rr = 0; rr < 8; ++rr) {
            const int rl = (rr << 3) + w;     // row_local 0..63
            const float* Ij = I + (size_t)(n0 + rl) * DD + c * 8;  // wave: 2KB contiguous
            float4 v0 = ((const float4*)Ij)[0];
            float4 v1 = ((const float4*)Ij)[1];
            float iv[8] = {v0.x, v0.y, v0.z, v0.w, v1.x, v1.y, v1.z, v1.w};

            float t[4] = {0.f, 0.f, 0.f, 0.f};
#pragma unroll
            for (int s = 0; s < 8; ++s) {
                float v = iv[s];
#pragma unroll
                for (int d = 0; d < 4; ++d)
                    t[d] = __fmaf_rn(v, sA[((s << 2) + d) * 64 + c], t[d]);
            }

            float th[NNODES];
#pragma unroll
            for (int i = 0; i < NNODES; ++i) {
                float h = __fsub_rn(t[lvl[i]], sT[c * NNODES + i]);
                th[i] = xla_tanhf(h);
            }

            int best = 0;
            float bestv = -3.0e38f;
#pragma unroll
            for (int k = 0; k < KK; ++k) {
                int node = 0;
                float s = 0.f;
#pragma unroll
                for (int l = 0; l < 4; ++l) {
                    int bit = (k >> (3 - l)) & 1;
                    s = __fadd_rn(s, bit ? th[node] : -th[node]);
                    node = 2 * node + 1 + bit;
                }
                if (s > bestv) { bestv = s; best = k; }   // strict >: first-max
            }
            // byte (rl>>4) of word [(rl&15)*68 + c]
            ((unsigned char*)&sCodes[(rl & 15) * 68 + c])[rl >> 4] = (unsigned char)best;
        }
    }
    __syncthreads();

    // ---------------- decode: one-hot fp16 MFMA GEMM ----------------
    const int r15  = lane & 15;                 // A row index within n-tile
    const int sb   = ((lane >> 4) & 1) << 3;    // slot base (0 or 8) of lane's k-window
    const int chi  = lane >> 5;                 // which of the 2 subspaces per k-step
    const int mtg0 = m0 >> 4;

    f32x4 acc[4][2];
#pragma unroll
    for (int nt = 0; nt < 4; ++nt) {
        acc[nt][0] = (f32x4){0.f, 0.f, 0.f, 0.f};
        acc[nt][1] = (f32x4){0.f, 0.f, 0.f, 0.f};
    }

    const uint4* Bp = Bpk + (size_t)mtg0 * 64 + lane;   // + (ks*32+mt)*64 per frag
    const unsigned* codeRow = sCodes + r15 * 68;        // + (2*ks + chi) per k-step

    // prologue: preload ks=0,1 B frags + code words
    uint4 b0m0 = Bp[(0 * 32 + 0) * 64], b0m1 = Bp[(0 * 32 + 1) * 64];
    uint4 b1m0 = Bp[(1 * 32 + 0) * 64], b1m1 = Bp[(1 * 32 + 1) * 64];
    unsigned cw0 = codeRow[0 + chi];
    unsigned cw1 = codeRow[2 + chi];

    for (int ks = 0; ks < 32; ks += 2) {
        uint4 n0m0, n0m1, n1m0, n1m1;
        unsigned nw0, nw1;
        const bool more = (ks + 2) < 32;
        if (more) {
            n0m0 = Bp[((ks + 2) * 32 + 0) * 64];
            n0m1 = Bp[((ks + 2) * 32 + 1) * 64];
            n1m0 = Bp[((ks + 3) * 32 + 0) * 64];
            n1m1 = Bp[((ks + 3) * 32 + 1) * 64];
            nw0 = codeRow[(ks + 2) * 2 + chi];
            nw1 = codeRow[(ks + 3) * 2 + chi];
        }

        // ---- k-step ks: one-hot A from cw0, MFMA vs b0m0/b0m1 ----
        {
            half8 a[4];
#pragma unroll
            for (int nt = 0; nt < 4; ++nt) {
                unsigned ud  = ((cw0 >> (nt << 3)) & 255u) - (unsigned)sb;
                unsigned ud2 = ud - 4u;
                u64 lo = (ud  < 4u) ? (0x3C00ull << ((ud  & 3u) << 4)) : 0ull;
                u64 hi = (ud2 < 4u) ? (0x3C00ull << ((ud2 & 3u) << 4)) : 0ull;
                union { u64 q[2]; half8 h; } uu; uu.q[0] = lo; uu.q[1] = hi;
                a[nt] = uu.h;
            }
            union { uint4 u; half8 h; } bb0, bb1; bb0.u = b0m0; bb1.u = b0m1;
#pragma unroll
            for (int nt = 0; nt < 4; ++nt) {
                acc[nt][0] = __builtin_amdgcn_mfma_f32_16x16x32_f16(a[nt], bb0.h, acc[nt][0], 0, 0, 0);
                acc[nt][1] = __builtin_amdgcn_mfma_f32_16x16x32_f16(a[nt], bb1.h, acc[nt][1], 0, 0, 0);
            }
        }

        // ---- k-step ks+1: one-hot A from cw1, MFMA vs b1m0/b1m1 ----
        {
            half8 a[4];
#pragma unroll
            for (int nt = 0; nt < 4; ++nt) {
                unsigned ud  = ((cw1 >> (nt << 3)) & 255u) - (unsigned)sb;
                unsigned ud2 = ud - 4u;
                u64 lo = (ud  < 4u) ? (0x3C00ull << ((ud  & 3u) << 4)) : 0ull;
                u64 hi = (ud2 < 4u) ? (0x3C00ull << ((ud2 & 3u) << 4)) : 0ull;
                union { u64 q[2]; half8 h; } uu; uu.q[0] = lo; uu.q[1] = hi;
                a[nt] = uu.h;
            }
            union { uint4 u; half8 h; } bb0, bb1; bb0.u = b1m0; bb1.u = b1m1;
#pragma unroll
            for (int nt = 0; nt < 4; ++nt) {
                acc[nt][0] = __builtin_amdgcn_mfma_f32_16x16x32_f16(a[nt], bb0.h, acc[nt][0], 0, 0, 0);
                acc[nt][1] = __builtin_amdgcn_mfma_f32_16x16x32_f16(a[nt], bb1.h, acc[nt][1], 0, 0, 0);
            }
        }

        if (more) {
            b0m0 = n0m0; b0m1 = n0m1; b1m0 = n1m0; b1m1 = n1m1;
            cw0 = nw0; cw1 = nw1;
        }
    }

    // ---------------- epilogue: D layout col=lane&15, row=(lane>>4)*4+reg ----------------
    const int rbase = (lane >> 4) << 2;
#pragma unroll
    for (int nt = 0; nt < 4; ++nt) {
#pragma unroll
        for (int r = 0; r < 4; ++r) {
            float* o = out + (size_t)(n0 + (nt << 4) + rbase + r) * MM + m0 + r15;
            o[0]  = acc[nt][0][r];
            o[16] = acc[nt][1][r];
        }
    }
}

// ---------------------------------------------------------------------------
extern "C" void kernel_launch(void* const* d_in, const int* in_sizes, int n_in,
                              void* d_out, int out_size, void* d_ws, size_t ws_size,
                              hipStream_t stream) {
    const float* I = (const float*)d_in[0];  // (N, D) fp32
    const float* A = (const float*)d_in[1];  // (C, 8, 4) fp32
    const float* T = (const float*)d_in[2];  // (C*15,) fp32
    const float* L = (const float*)d_in[3];  // (M, C, K) fp32
    // d_in[4] = S, d_in[5] = B: structural constants, hard-coded.

    uint4* Bpk = (uint4*)d_ws;               // 1 MB fp16 LUT in MFMA-B fragment order
    float* out = (float*)d_out;              // (N, M) fp32

    hipLaunchKernelGGL(pack_bfrag, dim3(256), dim3(256), 0, stream, L, Bpk);
    hipLaunchKernelGGL(fused_mfma, dim3(512), dim3(512), 0, stream, I, A, T, Bpk, out);
}

// Round 3
// 136.613 us; speedup vs baseline: 1.3336x; 1.3336x over previous
//
#include <hip/hip_runtime.h>
#include <hip/hip_fp16.h>
#include <math.h>

#define CC 64
#define KK 16
#define NNODES 15
#define DD 512      // input feature dim
#define MM 512      // output dim
#define NN 16384    // rows

typedef _Float16 half8 __attribute__((ext_vector_type(8)));
typedef float f32x4 __attribute__((ext_vector_type(4)));
typedef unsigned long long u64;

// ---------------------------------------------------------------------------
// XLA/Eigen fast-tanh for f32 (bit-exact vs JAX's jnp.tanh lowering).
// ---------------------------------------------------------------------------
__device__ __forceinline__ float xla_tanhf(float x) {
    const float kMax = 7.90531110763549805f;
    bool tiny = fabsf(x) < 0.0004f;
    float xc = fminf(fmaxf(x, -kMax), kMax);
    float x2 = __fmul_rn(xc, xc);
    float p = __fmaf_rn(x2, -2.76076847742355e-16f, 2.00018790482477e-13f);
    p = __fmaf_rn(x2, p, -8.60467152213735e-11f);
    p = __fmaf_rn(x2, p, 5.12229709037114e-08f);
    p = __fmaf_rn(x2, p, 1.48572235717979e-05f);
    p = __fmaf_rn(x2, p, 6.37261928875436e-04f);
    p = __fmaf_rn(x2, p, 4.89352455891786e-03f);
    p = __fmul_rn(xc, p);
    float q = __fmaf_rn(x2, 1.19825839466702e-06f, 1.18534705686654e-04f);
    q = __fmaf_rn(x2, q, 2.26843463243900e-03f);
    q = __fmaf_rn(x2, q, 4.89352518554385e-03f);
    return tiny ? x : __fdiv_rn(p, q);
}

// ---------------------------------------------------------------------------
// Kernel 1: pack L (M, C, K) fp32 -> Bpk fp16 in MFMA-B fragment order.
// B operand of mfma_f32_16x16x32_f16: lane l holds B[k=(l>>4)*8+j][col=l&15],
// j = 0..7 packed in 4 VGPRs. Layout: Bpk[ks][mtile][lane] = uint4 (8 halves).
// (round-1 verified: fused_mfma passed with this layout)
// ---------------------------------------------------------------------------
__global__ __launch_bounds__(256) void pack_bfrag(const float* __restrict__ L,
                                                  uint4* __restrict__ Bpk) {
    const int t    = blockIdx.x * 256 + threadIdx.x;  // 0..65535
    const int lane = t & 63;
    const int mtg  = (t >> 6) & 31;                   // global m-tile 0..31
    const int ks   = t >> 11;                         // k-step 0..31
    const int kbase = ks * 32 + ((lane >> 4) << 3);   // 8-aligned k window
    const int c     = kbase >> 4;                     // subspace
    const int slot0 = kbase & 15;                     // 0 or 8
    const int m     = (mtg << 4) + (lane & 15);

    const float* src = L + ((size_t)m * CC + c) * KK + slot0;
    float4 v0 = ((const float4*)src)[0];
    float4 v1 = ((const float4*)src)[1];
    union { half8 h; uint4 u; } pk;
    pk.h[0] = (_Float16)v0.x; pk.h[1] = (_Float16)v0.y;
    pk.h[2] = (_Float16)v0.z; pk.h[3] = (_Float16)v0.w;
    pk.h[4] = (_Float16)v1.x; pk.h[5] = (_Float16)v1.y;
    pk.h[6] = (_Float16)v1.z; pk.h[7] = (_Float16)v1.w;
    Bpk[t] = pk.u;
}

// ---------------------------------------------------------------------------
// Kernel 2: FUSED encode + MFMA decode.
// Block: 64 rows x 256 cols, 8 waves (512 thr); wave = 64 rows x 32 cols
// (4 nt x 2 mt). Grid 512.
//
// __launch_bounds__(512, 2): ROUND-2 EVIDENCE — the 2nd arg behaves as CUDA
// minBlocksPerCU on this toolchain. (512,4) forced a 64-VGPR cap -> ~100
// live VGPRs spilled to scratch -> FETCH 36->108MB, WRITE 33->141MB, 107us.
// (512,2) = 16 waves/CU = 4 waves/SIMD, 128-VGPR cap: fits ~105 live regs.
//
// sCodes packed as u32[(r15*68)+c] (byte nt = code of row nt*16+r15): one
// ds_read_b32 per 4 one-hot builds, <=2-way banks. B frags + code words
// software-pipelined one full iteration (2 k-steps) ahead of the MFMAs.
// ---------------------------------------------------------------------------
__global__ __launch_bounds__(512, 2) void fused_mfma(const float* __restrict__ I,
                                                     const float* __restrict__ A,
                                                     const float* __restrict__ T,
                                                     const uint4* __restrict__ Bpk,
                                                     float* __restrict__ out) {
    __shared__ float sA[32 * 64];              // TRANSPOSED: [s*4+d][c]
    __shared__ float sT[CC * NNODES];
    __shared__ unsigned sCodes[16 * 68];       // [r15][c] u32: 4 nt codes packed

    const int tid = threadIdx.x;
    for (int i = tid; i < CC * 32; i += 512) sA[(i & 31) * 64 + (i >> 5)] = A[i];
    for (int i = tid; i < CC * NNODES; i += 512) sT[i] = T[i];
    __syncthreads();

    const int w    = tid >> 6;        // wave 0..7
    const int lane = tid & 63;
    const int n0 = (blockIdx.x >> 1) * 64;
    const int m0 = (blockIdx.x & 1) * 256 + w * 32;

    // ---------------- encode (bit-exact round-5 math; 8 rows/thread) ----------------
    {
        const int c = lane;
        const int lvl[NNODES] = {0, 1, 1, 2, 2, 2, 2, 3, 3, 3, 3, 3, 3, 3, 3};
#pragma unroll 2
        for (int rr = 0; rr < 8; ++rr) {
            const int rl = (rr << 3) + w;     // row_local 0..63
            const float* Ij = I + (size_t)(n0 + rl) * DD + c * 8;  // wave: 2KB contiguous
            float4 v0 = ((const float4*)Ij)[0];
            float4 v1 = ((const float4*)Ij)[1];
            float iv[8] = {v0.x, v0.y, v0.z, v0.w, v1.x, v1.y, v1.z, v1.w};

            float t[4] = {0.f, 0.f, 0.f, 0.f};
#pragma unroll
            for (int s = 0; s < 8; ++s) {
                float v = iv[s];
#pragma unroll
                for (int d = 0; d < 4; ++d)
                    t[d] = __fmaf_rn(v, sA[((s << 2) + d) * 64 + c], t[d]);
            }

            float th[NNODES];
#pragma unroll
            for (int i = 0; i < NNODES; ++i) {
                float h = __fsub_rn(t[lvl[i]], sT[c * NNODES + i]);
                th[i] = xla_tanhf(h);
            }

            int best = 0;
            float bestv = -3.0e38f;
#pragma unroll
            for (int k = 0; k < KK; ++k) {
                int node = 0;
                float s = 0.f;
#pragma unroll
                for (int l = 0; l < 4; ++l) {
                    int bit = (k >> (3 - l)) & 1;
                    s = __fadd_rn(s, bit ? th[node] : -th[node]);
                    node = 2 * node + 1 + bit;
                }
                if (s > bestv) { bestv = s; best = k; }   // strict >: first-max
            }
            // byte (rl>>4) of word [(rl&15)*68 + c]
            ((unsigned char*)&sCodes[(rl & 15) * 68 + c])[rl >> 4] = (unsigned char)best;
        }
    }
    __syncthreads();

    // ---------------- decode: one-hot fp16 MFMA GEMM ----------------
    const int r15  = lane & 15;                 // A row index within n-tile
    const int sb   = ((lane >> 4) & 1) << 3;    // slot base (0 or 8) of lane's k-window
    const int chi  = lane >> 5;                 // which of the 2 subspaces per k-step
    const int mtg0 = m0 >> 4;

    f32x4 acc[4][2];
#pragma unroll
    for (int nt = 0; nt < 4; ++nt) {
        acc[nt][0] = (f32x4){0.f, 0.f, 0.f, 0.f};
        acc[nt][1] = (f32x4){0.f, 0.f, 0.f, 0.f};
    }

    const uint4* Bp = Bpk + (size_t)mtg0 * 64 + lane;   // + (ks*32+mt)*64 per frag
    const unsigned* codeRow = sCodes + r15 * 68;        // + (2*ks + chi) per k-step

    // prologue: preload ks=0,1 B frags + code words
    uint4 b0m0 = Bp[(0 * 32 + 0) * 64], b0m1 = Bp[(0 * 32 + 1) * 64];
    uint4 b1m0 = Bp[(1 * 32 + 0) * 64], b1m1 = Bp[(1 * 32 + 1) * 64];
    unsigned cw0 = codeRow[0 + chi];
    unsigned cw1 = codeRow[2 + chi];

    for (int ks = 0; ks < 32; ks += 2) {
        uint4 n0m0, n0m1, n1m0, n1m1;
        unsigned nw0, nw1;
        const bool more = (ks + 2) < 32;
        if (more) {
            n0m0 = Bp[((ks + 2) * 32 + 0) * 64];
            n0m1 = Bp[((ks + 2) * 32 + 1) * 64];
            n1m0 = Bp[((ks + 3) * 32 + 0) * 64];
            n1m1 = Bp[((ks + 3) * 32 + 1) * 64];
            nw0 = codeRow[(ks + 2) * 2 + chi];
            nw1 = codeRow[(ks + 3) * 2 + chi];
        }

        // ---- k-step ks: one-hot A from cw0, MFMA vs b0m0/b0m1 ----
        {
            half8 a[4];
#pragma unroll
            for (int nt = 0; nt < 4; ++nt) {
                unsigned ud  = ((cw0 >> (nt << 3)) & 255u) - (unsigned)sb;
                unsigned ud2 = ud - 4u;
                u64 lo = (ud  < 4u) ? (0x3C00ull << ((ud  & 3u) << 4)) : 0ull;
                u64 hi = (ud2 < 4u) ? (0x3C00ull << ((ud2 & 3u) << 4)) : 0ull;
                union { u64 q[2]; half8 h; } uu; uu.q[0] = lo; uu.q[1] = hi;
                a[nt] = uu.h;
            }
            union { uint4 u; half8 h; } bb0, bb1; bb0.u = b0m0; bb1.u = b0m1;
#pragma unroll
            for (int nt = 0; nt < 4; ++nt) {
                acc[nt][0] = __builtin_amdgcn_mfma_f32_16x16x32_f16(a[nt], bb0.h, acc[nt][0], 0, 0, 0);
                acc[nt][1] = __builtin_amdgcn_mfma_f32_16x16x32_f16(a[nt], bb1.h, acc[nt][1], 0, 0, 0);
            }
        }

        // ---- k-step ks+1: one-hot A from cw1, MFMA vs b1m0/b1m1 ----
        {
            half8 a[4];
#pragma unroll
            for (int nt = 0; nt < 4; ++nt) {
                unsigned ud  = ((cw1 >> (nt << 3)) & 255u) - (unsigned)sb;
                unsigned ud2 = ud - 4u;
                u64 lo = (ud  < 4u) ? (0x3C00ull << ((ud  & 3u) << 4)) : 0ull;
                u64 hi = (ud2 < 4u) ? (0x3C00ull << ((ud2 & 3u) << 4)) : 0ull;
                union { u64 q[2]; half8 h; } uu; uu.q[0] = lo; uu.q[1] = hi;
                a[nt] = uu.h;
            }
            union { uint4 u; half8 h; } bb0, bb1; bb0.u = b1m0; bb1.u = b1m1;
#pragma unroll
            for (int nt = 0; nt < 4; ++nt) {
                acc[nt][0] = __builtin_amdgcn_mfma_f32_16x16x32_f16(a[nt], bb0.h, acc[nt][0], 0, 0, 0);
                acc[nt][1] = __builtin_amdgcn_mfma_f32_16x16x32_f16(a[nt], bb1.h, acc[nt][1], 0, 0, 0);
            }
        }

        if (more) {
            b0m0 = n0m0; b0m1 = n0m1; b1m0 = n1m0; b1m1 = n1m1;
            cw0 = nw0; cw1 = nw1;
        }
    }

    // ---------------- epilogue: D layout col=lane&15, row=(lane>>4)*4+reg ----------------
    const int rbase = (lane >> 4) << 2;
#pragma unroll
    for (int nt = 0; nt < 4; ++nt) {
#pragma unroll
        for (int r = 0; r < 4; ++r) {
            float* o = out + (size_t)(n0 + (nt << 4) + rbase + r) * MM + m0 + r15;
            o[0]  = acc[nt][0][r];
            o[16] = acc[nt][1][r];
        }
    }
}

// ---------------------------------------------------------------------------
extern "C" void kernel_launch(void* const* d_in, const int* in_sizes, int n_in,
                              void* d_out, int out_size, void* d_ws, size_t ws_size,
                              hipStream_t stream) {
    const float* I = (const float*)d_in[0];  // (N, D) fp32
    const float* A = (const float*)d_in[1];  // (C, 8, 4) fp32
    const float* T = (const float*)d_in[2];  // (C*15,) fp32
    const float* L = (const float*)d_in[3];  // (M, C, K) fp32
    // d_in[4] = S, d_in[5] = B: structural constants, hard-coded.

    uint4* Bpk = (uint4*)d_ws;               // 1 MB fp16 LUT in MFMA-B fragment order
    float* out = (float*)d_out;              // (N, M) fp32

    hipLaunchKernelGGL(pack_bfrag, dim3(256), dim3(256), 0, stream, L, Bpk);
    hipLaunchKernelGGL(fused_mfma, dim3(512), dim3(512), 0, stream, I, A, T, Bpk, out);
}

// Round 4
// 132.957 us; speedup vs baseline: 1.3702x; 1.0275x over previous
//
#include <hip/hip_runtime.h>
#include <hip/hip_fp16.h>
#include <math.h>

#define CC 64
#define KK 16
#define NNODES 15
#define DD 512      // input feature dim
#define MM 512      // output dim
#define NN 16384    // rows

typedef _Float16 half8 __attribute__((ext_vector_type(8)));
typedef float f32x4 __attribute__((ext_vector_type(4)));
typedef unsigned long long u64;

// ---------------------------------------------------------------------------
// XLA/Eigen fast-tanh for f32 (bit-exact vs JAX's jnp.tanh lowering).
// ---------------------------------------------------------------------------
__device__ __forceinline__ float xla_tanhf(float x) {
    const float kMax = 7.90531110763549805f;
    bool tiny = fabsf(x) < 0.0004f;
    float xc = fminf(fmaxf(x, -kMax), kMax);
    float x2 = __fmul_rn(xc, xc);
    float p = __fmaf_rn(x2, -2.76076847742355e-16f, 2.00018790482477e-13f);
    p = __fmaf_rn(x2, p, -8.60467152213735e-11f);
    p = __fmaf_rn(x2, p, 5.12229709037114e-08f);
    p = __fmaf_rn(x2, p, 1.48572235717979e-05f);
    p = __fmaf_rn(x2, p, 6.37261928875436e-04f);
    p = __fmaf_rn(x2, p, 4.89352455891786e-03f);
    p = __fmul_rn(xc, p);
    float q = __fmaf_rn(x2, 1.19825839466702e-06f, 1.18534705686654e-04f);
    q = __fmaf_rn(x2, q, 2.26843463243900e-03f);
    q = __fmaf_rn(x2, q, 4.89352518554385e-03f);
    return tiny ? x : __fdiv_rn(p, q);
}

// ---------------------------------------------------------------------------
// Kernel 1: pack L (M, C, K) fp32 -> Bpk fp16 in MFMA-B fragment order.
// B operand of mfma_f32_16x16x32_f16: lane l holds B[k=(l>>4)*8+j][col=l&15],
// j = 0..7 packed in 4 VGPRs. Layout: Bpk[ks][mtile][lane] = uint4 (8 halves).
// (round-1 verified: fused_mfma passed with this layout)
// ---------------------------------------------------------------------------
__global__ __launch_bounds__(256) void pack_bfrag(const float* __restrict__ L,
                                                  uint4* __restrict__ Bpk) {
    const int t    = blockIdx.x * 256 + threadIdx.x;  // 0..65535
    const int lane = t & 63;
    const int mtg  = (t >> 6) & 31;                   // global m-tile 0..31
    const int ks   = t >> 11;                         // k-step 0..31
    const int kbase = ks * 32 + ((lane >> 4) << 3);   // 8-aligned k window
    const int c     = kbase >> 4;                     // subspace
    const int slot0 = kbase & 15;                     // 0 or 8
    const int m     = (mtg << 4) + (lane & 15);

    const float* src = L + ((size_t)m * CC + c) * KK + slot0;
    float4 v0 = ((const float4*)src)[0];
    float4 v1 = ((const float4*)src)[1];
    union { half8 h; uint4 u; } pk;
    pk.h[0] = (_Float16)v0.x; pk.h[1] = (_Float16)v0.y;
    pk.h[2] = (_Float16)v0.z; pk.h[3] = (_Float16)v0.w;
    pk.h[4] = (_Float16)v1.x; pk.h[5] = (_Float16)v1.y;
    pk.h[6] = (_Float16)v1.z; pk.h[7] = (_Float16)v1.w;
    Bpk[t] = pk.u;
}

// ---------------------------------------------------------------------------
// Kernel 2: FUSED encode + MFMA decode — duplication-elimination restructure.
// Block: 64 rows x 512 cols (FULL M), 1024 thr = 16 waves (Wn=4 x Wm=4);
// wave = 1 n-tile x 8 m-tiles. Grid 256 = 1 block/CU, 16 waves/CU, 4/SIMD.
//
// R3 evidence: 8 waves built IDENTICAL one-hot A frags (VALUBusy 55% vs
// MfmaUtil 10.5%) and each 64-row stripe was encoded twice (2 m-half
// blocks). This layout: encode once (4 rows/thread), A-build once per
// wave per ks (byte wn of packed code word), and the 4 waves sharing wm
// read IDENTICAL B frags -> L1 hits + L2 traffic /4.
//
// __launch_bounds__(1024, 1): ROUND-2/3 EVIDENCE — arg2 behaves as CUDA
// minBlocksPerCU. 1 block/CU = 16 waves/CU -> 128-VGPR cap; kernel needs
// ~116 (acc 32 + B ping-pong 64 + misc). DO NOT raise arg2: (512,4) spilled
// to scratch (FETCH 36->108MB) in round 2.
// ---------------------------------------------------------------------------
__global__ __launch_bounds__(1024, 1) void fused_mfma(const float* __restrict__ I,
                                                      const float* __restrict__ A,
                                                      const float* __restrict__ T,
                                                      const uint4* __restrict__ Bpk,
                                                      float* __restrict__ out) {
    __shared__ float sA[32 * 64];              // TRANSPOSED: [s*4+d][c]
    __shared__ float sT[CC * NNODES];
    __shared__ unsigned sCodes[16 * 68];       // [r15][c] u32: byte rr = code of row rr*16+r15

    const int tid = threadIdx.x;
    for (int i = tid; i < CC * 32; i += 1024) sA[(i & 31) * 64 + (i >> 5)] = A[i];
    for (int i = tid; i < CC * NNODES; i += 1024) sT[i] = T[i];
    __syncthreads();

    const int w    = tid >> 6;        // wave 0..15
    const int lane = tid & 63;
    const int n0   = blockIdx.x * 64;

    // ---------------- encode (bit-exact round-5 math; 4 rows/thread) ----------------
    // Thread (w, lane): subspace c = lane, rows rl = rr*16 + w (rr = 0..3).
    // Codes packed into one u32 (byte rr) -> single conflict-free ds_write_b32.
    {
        const int c = lane;
        const int lvl[NNODES] = {0, 1, 1, 2, 2, 2, 2, 3, 3, 3, 3, 3, 3, 3, 3};
        unsigned codeWord = 0;
#pragma unroll 2
        for (int rr = 0; rr < 4; ++rr) {
            const int rl = (rr << 4) + w;     // row_local 0..63
            const float* Ij = I + (size_t)(n0 + rl) * DD + c * 8;  // wave: 2KB contiguous
            float4 v0 = ((const float4*)Ij)[0];
            float4 v1 = ((const float4*)Ij)[1];
            float iv[8] = {v0.x, v0.y, v0.z, v0.w, v1.x, v1.y, v1.z, v1.w};

            float t[4] = {0.f, 0.f, 0.f, 0.f};
#pragma unroll
            for (int s = 0; s < 8; ++s) {
                float v = iv[s];
#pragma unroll
                for (int d = 0; d < 4; ++d)
                    t[d] = __fmaf_rn(v, sA[((s << 2) + d) * 64 + c], t[d]);
            }

            float th[NNODES];
#pragma unroll
            for (int i = 0; i < NNODES; ++i) {
                float h = __fsub_rn(t[lvl[i]], sT[c * NNODES + i]);
                th[i] = xla_tanhf(h);
            }

            int best = 0;
            float bestv = -3.0e38f;
#pragma unroll
            for (int k = 0; k < KK; ++k) {
                int node = 0;
                float s = 0.f;
#pragma unroll
                for (int l = 0; l < 4; ++l) {
                    int bit = (k >> (3 - l)) & 1;
                    s = __fadd_rn(s, bit ? th[node] : -th[node]);
                    node = 2 * node + 1 + bit;
                }
                if (s > bestv) { bestv = s; best = k; }   // strict >: first-max
            }
            codeWord |= ((unsigned)best) << (rr << 3);
        }
        sCodes[w * 68 + c] = codeWord;    // w==r15 of these rows; 2-way banks: free
    }
    __syncthreads();

    // ---------------- decode: one-hot fp16 MFMA GEMM ----------------
    const int wn   = w & 3;                     // n-tile index (also code byte index)
    const int wm   = w >> 2;                    // 128-col strip
    const int r15  = lane & 15;                 // A row index within n-tile
    const int sb   = ((lane >> 4) & 1) << 3;    // slot base (0 or 8) of lane's k-window
    const int chi  = lane >> 5;                 // which of the 2 subspaces per k-step

    f32x4 acc[8];
#pragma unroll
    for (int mt = 0; mt < 8; ++mt) acc[mt] = (f32x4){0.f, 0.f, 0.f, 0.f};

    const uint4* Bp = Bpk + (size_t)(wm * 8) * 64 + lane;  // + (ks*32 + mt)*64 per frag
    const unsigned* codeRow = sCodes + r15 * 68;           // + (2*ks + chi) per k-step
    const int wnsh = wn << 3;

    // ping-pong B buffers (no register moves): bX holds even ks, bY odd ks
    uint4 bX[8], bY[8];
#pragma unroll
    for (int mt = 0; mt < 8; ++mt) bX[mt] = Bp[mt * 64];
    unsigned cwA = codeRow[chi];
    unsigned cwB;

    for (int ks = 0; ks < 32; ks += 2) {
        // prefetch ks+1 (ks <= 30: always valid)
#pragma unroll
        for (int mt = 0; mt < 8; ++mt) bY[mt] = Bp[((ks + 1) * 32 + mt) * 64];
        cwB = codeRow[(ks + 1) * 2 + chi];

        // ---- k-step ks: one-hot A from byte wn of cwA, MFMA vs bX ----
        {
            unsigned ud  = ((cwA >> wnsh) & 255u) - (unsigned)sb;
            unsigned ud2 = ud - 4u;
            u64 lo = (ud  < 4u) ? (0x3C00ull << ((ud  & 3u) << 4)) : 0ull;
            u64 hi = (ud2 < 4u) ? (0x3C00ull << ((ud2 & 3u) << 4)) : 0ull;
            union { u64 q[2]; half8 h; } uu; uu.q[0] = lo; uu.q[1] = hi;
#pragma unroll
            for (int mt = 0; mt < 8; ++mt) {
                union { uint4 u; half8 h; } bb; bb.u = bX[mt];
                acc[mt] = __builtin_amdgcn_mfma_f32_16x16x32_f16(uu.h, bb.h, acc[mt], 0, 0, 0);
            }
        }

        if (ks + 2 < 32) {
#pragma unroll
            for (int mt = 0; mt < 8; ++mt) bX[mt] = Bp[((ks + 2) * 32 + mt) * 64];
            cwA = codeRow[(ks + 2) * 2 + chi];
        }

        // ---- k-step ks+1: one-hot A from byte wn of cwB, MFMA vs bY ----
        {
            unsigned ud  = ((cwB >> wnsh) & 255u) - (unsigned)sb;
            unsigned ud2 = ud - 4u;
            u64 lo = (ud  < 4u) ? (0x3C00ull << ((ud  & 3u) << 4)) : 0ull;
            u64 hi = (ud2 < 4u) ? (0x3C00ull << ((ud2 & 3u) << 4)) : 0ull;
            union { u64 q[2]; half8 h; } uu; uu.q[0] = lo; uu.q[1] = hi;
#pragma unroll
            for (int mt = 0; mt < 8; ++mt) {
                union { uint4 u; half8 h; } bb; bb.u = bY[mt];
                acc[mt] = __builtin_amdgcn_mfma_f32_16x16x32_f16(uu.h, bb.h, acc[mt], 0, 0, 0);
            }
        }
    }

    // ---------------- epilogue: D layout col=lane&15, row=(lane>>4)*4+reg ----------------
    const int rbase = (lane >> 4) << 2;
#pragma unroll
    for (int mt = 0; mt < 8; ++mt) {
#pragma unroll
        for (int r = 0; r < 4; ++r) {
            out[(size_t)(n0 + (wn << 4) + rbase + r) * MM + (wm << 7) + (mt << 4) + r15] = acc[mt][r];
        }
    }
}

// ---------------------------------------------------------------------------
extern "C" void kernel_launch(void* const* d_in, const int* in_sizes, int n_in,
                              void* d_out, int out_size, void* d_ws, size_t ws_size,
                              hipStream_t stream) {
    const float* I = (const float*)d_in[0];  // (N, D) fp32
    const float* A = (const float*)d_in[1];  // (C, 8, 4) fp32
    const float* T = (const float*)d_in[2];  // (C*15,) fp32
    const float* L = (const float*)d_in[3];  // (M, C, K) fp32
    // d_in[4] = S, d_in[5] = B: structural constants, hard-coded.

    uint4* Bpk = (uint4*)d_ws;               // 1 MB fp16 LUT in MFMA-B fragment order
    float* out = (float*)d_out;              // (N, M) fp32

    hipLaunchKernelGGL(pack_bfrag, dim3(256), dim3(256), 0, stream, L, Bpk);
    hipLaunchKernelGGL(fused_mfma, dim3(NN / 64), dim3(1024), 0, stream, I, A, T, Bpk, out);
}